// Round 1
// 452.015 us; speedup vs baseline: 1.1109x; 1.1109x over previous
//
#include <hip/hip_runtime.h>

typedef unsigned short u16;
typedef short bf16x8 __attribute__((ext_vector_type(8)));
typedef float f32x4 __attribute__((ext_vector_type(4)));
typedef u16 u16x4 __attribute__((ext_vector_type(4)));
typedef u16 u16x8 __attribute__((ext_vector_type(8)));
typedef unsigned u32x4 __attribute__((ext_vector_type(4)));

__device__ __forceinline__ float b2f(u16 v) {
  union { unsigned u; float f; } x; x.u = ((unsigned)v) << 16; return x.f;
}
__device__ __forceinline__ u16 f2b(float f) {
  unsigned u = __float_as_uint(f);
  unsigned r = (u + 0x7FFFu + ((u >> 16) & 1u)) >> 16;
  return (u16)r;
}
// dtype-agnostic input read: bf==1 -> bf16, bf==0 -> f32
__device__ __forceinline__ float rin(const void* p, size_t i, int bf) {
  return bf ? b2f(((const u16*)p)[i]) : ((const float*)p)[i];
}
__device__ __forceinline__ void async16(const void* g, void* l) {
  __builtin_amdgcn_global_load_lds((const __attribute__((address_space(1))) unsigned*)g,
                                   (__attribute__((address_space(3))) unsigned*)l, 16, 0, 0);
}
// per-block dtype detection: wave 0 inspects w0's first 64 words (L2-resident),
// broadcasts via LDS. bf16 data -> every low-u16 has plausible small-bf16 exponent.
__device__ __forceinline__ int detect_bf(const unsigned* __restrict__ w0raw, int tid, int* shflag) {
  if (tid < 64) {
    const unsigned lo = w0raw[tid] & 0xFFFFu;
    const unsigned e = (lo >> 7) & 0xFFu;
    const unsigned long long bad = __ballot(e < 100u || e > 126u);
    if (tid == 0) *shflag = (bad == 0ull) ? 1 : 0;
  }
  __syncthreads();
  return *shflag;
}

// ---- all three style GEMMs in one launch: s[b,i] = sum_z w[b,z]*sW[i,z] + sB[i]
__global__ void styleall_kernel(const void* __restrict__ w,
                                const void* __restrict__ sW0, const void* __restrict__ sB0,
                                const void* __restrict__ sW1, const void* __restrict__ sB1,
                                const void* __restrict__ sWR, const void* __restrict__ sBR,
                                float* __restrict__ s0, float* __restrict__ s1,
                                float* __restrict__ sR, const unsigned* __restrict__ w0raw) {
  __shared__ int shflag;
  const int tid = threadIdx.x;
  const int bf = detect_bf(w0raw, tid, &shflag);
  const int mat = blockIdx.z, b = blockIdx.y, oc = blockIdx.x;
  const void* sW = (mat == 0) ? sW0 : ((mat == 1) ? sW1 : sWR);
  const void* sB = (mat == 0) ? sB0 : ((mat == 1) ? sB1 : sBR);
  float* out = (mat == 0) ? s0 : ((mat == 1) ? s1 : sR);
  const int i = oc * 64 + (tid >> 2), q = tid & 3;
  float acc = 0.f;
  if (bf) {
    const u16* rp = (const u16*)sW + (size_t)i * 512 + q * 128;
    const u16* wp = (const u16*)w + b * 512 + q * 128;
    for (int z = 0; z < 128; z += 8) {
      u16x8 a = *(const u16x8*)(rp + z), c = *(const u16x8*)(wp + z);
#pragma unroll
      for (int j = 0; j < 8; ++j) acc += b2f(a[j]) * b2f(c[j]);
    }
  } else {
    const float* rp = (const float*)sW + (size_t)i * 512 + q * 128;
    const float* wp = (const float*)w + b * 512 + q * 128;
    for (int z = 0; z < 128; z += 4) {
      f32x4 a = *(const f32x4*)(rp + z), c = *(const f32x4*)(wp + z);
#pragma unroll
      for (int j = 0; j < 4; ++j) acc += a[j] * c[j];
    }
  }
  acc += __shfl_xor(acc, 1, 64);
  acc += __shfl_xor(acc, 2, 64);
  if (q == 0) out[b * 512 + i] = acc + rin(sB, i, bf);
}

// ---- demod (both layers in one launch, coalesced): block (o, layer).
__global__ void demod_kernel(const void* __restrict__ W0, const void* __restrict__ W1,
                             const float* __restrict__ s0, const float* __restrict__ s1,
                             float* __restrict__ dm0, float* __restrict__ dm1,
                             u16* __restrict__ Wp0, u16* __restrict__ Wp1,
                             const unsigned* __restrict__ w0raw) {
  __shared__ int shflag;
  __shared__ float wl[4608];
  __shared__ float wsq[512];
  const int tid = threadIdx.x, lane = tid & 63, wv = tid >> 6;
  const int bf = detect_bf(w0raw, tid, &shflag);
  const int o = blockIdx.x, layer = blockIdx.y;
  const void* W = layer ? W1 : W0;
  const float* s = layer ? s1 : s0;
  float* d = layer ? dm1 : dm0;
  u16* Wp = layer ? Wp1 : Wp0;

  if (bf) {
    const u16* src = (const u16*)W + (size_t)o * 4608;
    for (int e = tid; e < 576; e += 256) {
      u16x8 v = *(const u16x8*)(src + e * 8);
#pragma unroll
      for (int j = 0; j < 8; ++j) wl[e * 8 + j] = b2f(v[j]);
    }
  } else {
    const float* src = (const float*)W + (size_t)o * 4608;
    for (int e = tid; e < 1152; e += 256) {
      f32x4 v = *(const f32x4*)(src + e * 4);
#pragma unroll
      for (int j = 0; j < 4; ++j) wl[e * 4 + j] = v[j];
    }
  }
  __syncthreads();
  for (int i = tid; i < 512; i += 256) {
    float ss = 0.f;
#pragma unroll
    for (int t = 0; t < 9; ++t) {
      const float f = wl[i * 9 + t];
      ss += f * f;
      Wp[t * 262144 + o * 512 + i] = f2b(f);
    }
    wsq[i] = ss;
  }
  __syncthreads();
#pragma unroll
  for (int bb = 0; bb < 2; ++bb) {
    const int b = wv * 2 + bb;
    float part = 0.f;
    for (int i = lane; i < 512; i += 64) { const float sv = s[b * 512 + i]; part += wsq[i] * sv * sv; }
#pragma unroll
    for (int st = 1; st < 64; st <<= 1) part += __shfl_xor(part, st, 64);
    if (lane == 0) d[b * 512 + o] = rsqrtf(part + 1e-8f);
  }
}

// ---- prep: zero actB's halo ring only (interior is overwritten by conv0) + zbuf/rgbacc
__global__ void prep_kernel(u16* __restrict__ actB, u32x4* __restrict__ zr, int NB) {
  const int id = blockIdx.x, tid = threadIdx.x;
  if (id < NB * 65) {
    const int bl = id / 65, sub = id - bl * 65;
    const int c = sub * 256 + tid;      // 0..16639 : 260 ring px x 64 chunks
    const int px = c >> 6, seg = c & 63;
    int oy, ox;
    if (px < 66)       { oy = 0;  ox = px; }
    else if (px < 132) { oy = 65; ox = px - 66; }
    else { const int e = px - 132; oy = 1 + (e >> 1); ox = (e & 1) * 65; }
    u32x4 z = {0, 0, 0, 0};
    *(u32x4*)&actB[((size_t)(bl * 4356) + oy * 66 + ox) * 512 + seg * 8] = z;
  } else {
    const int c = (id - NB * 65) * 256 + tid;
    if (c < 24832) { u32x4 z = {0, 0, 0, 0}; zr[c] = z; }
  }
}

// ---- bilinear 2x upsample * s0 -> bf16 NHWC scratch [bl][4096][512] inside d_out x-region
__global__ void upsample_kernel(const void* __restrict__ maps, const float* __restrict__ s,
                                void* __restrict__ outb, int b_base,
                                const unsigned* __restrict__ w0raw) {
  __shared__ int shflag;
  __shared__ float it[32][2][33];
  const int tid = threadIdx.x;
  const int bf = detect_bf(w0raw, tid, &shflag);
  const size_t esz = bf ? 2 : 4;
  u16* xg = (u16*)((char*)outb + (98304 + (size_t)(b_base >> 2) * 8388608) * esz);
  const int oy = blockIdx.x;       // 0..63
  const int i0 = blockIdx.y * 32;  // channel chunk
  const int bl = blockIdx.z;       // local batch
  const int bg = b_base + bl;
  const int m = oy >> 1;
  int iy0, iy1; float wy0, wy1;
  if ((oy & 1) == 0) { iy0 = (m > 0) ? m - 1 : 0; iy1 = m; wy0 = 0.25f; wy1 = 0.75f; }
  else               { iy0 = m; iy1 = (m < 31) ? m + 1 : 31; wy0 = 0.75f; wy1 = 0.25f; }
#pragma unroll
  for (int k = 0; k < 8; ++k) {
    const int e = tid + k * 256;  // 32c x 2rows x 32x = 2048
    const int c = e >> 6, wsel = (e >> 5) & 1, x = e & 31;
    const int iy = wsel ? iy1 : iy0;
    it[c][wsel][x] = rin(maps, ((size_t)(bg * 512 + i0 + c) * 32 + iy) * 32 + x, bf);
  }
  __syncthreads();
#pragma unroll
  for (int k = 0; k < 8; ++k) {
    const int e = tid + k * 256;  // 64 xx * 32 c = 2048
    const int xx = e >> 5, c = e & 31;
    const int mx = xx >> 1;
    int ix0, ix1; float wx0, wx1;
    if ((xx & 1) == 0) { ix0 = (mx > 0) ? mx - 1 : 0; ix1 = mx; wx0 = 0.25f; wx1 = 0.75f; }
    else               { ix0 = mx; ix1 = (mx < 31) ? mx + 1 : 31; wx0 = 0.75f; wx1 = 0.25f; }
    const float r0 = wx0 * it[c][0][ix0] + wx1 * it[c][0][ix1];
    const float r1 = wx0 * it[c][1][ix0] + wx1 * it[c][1][ix1];
    const float v = (wy0 * r0 + wy1 * r1) * s[bg * 512 + i0 + c];
    xg[((size_t)(bl * 4096) + oy * 64 + xx) * 512 + i0 + c] = f2b(v);
  }
}

// ---- conv (both layers): 256x256 implicit-GEMM tile, BK=64, 8 waves (2Mx4N),
// 4-phase K-step schedule with counted vmcnt (never drained to 0 in steady state),
// XOR-swizzled LDS via pre-swizzled global_load_lds SOURCE addresses (linear dest),
// s_setprio around MFMA clusters, image-per-XCD block swizzle.
// K order: tap-major (t = s>>3), 64 K per step, 72 steps, double-buffered 128KB LDS.
//
// Staging pools per wave (2 instrs/phase, 8 per K-step, prefetching step s+1):
//   ph0: A-early (rows for qm=0)   ph1: B-even (rows for qn=0)
//   ph2: B-odd  (rows for qn=1)    ph3: A-late  (rows for qm=1)
// Waits (per-wave vmcnt, in-order retire): ph0-end vmcnt(4) -> B-odd of s done;
// ph1-end vmcnt(4) -> A-late of s done; ph3-end vmcnt(4) -> A-early+B-even of s+1
// done. Buffer WAR is safe: stages for s+1 only issue after the barrier that ends
// the last read of s-1 from the same buffer.
template <int L>
__global__ __launch_bounds__(512) void conv_kernel(
    void* __restrict__ outb, u16* __restrict__ actBp,
    const u16* __restrict__ Wp, const float* __restrict__ dmod,
    const void* __restrict__ bias, const void* __restrict__ nsc,
    const void* __restrict__ noise, const float* __restrict__ saux,
    const u16* __restrict__ zbuf, const void* __restrict__ rgbW,
    float* __restrict__ rgbacc, int b_base,
    const unsigned* __restrict__ w0raw) {
  __shared__ __attribute__((aligned(16))) u16 lds[65536];  // [2 dbuf][A 16K u16 | B 16K u16]
  __shared__ float rgbWl[L == 1 ? 1536 : 4];
  __shared__ int shflag;
  const int tid = threadIdx.x, lane = tid & 63, w = tid >> 6;
  const int bf = detect_bf(w0raw, tid, &shflag);
  const size_t esz = bf ? 2 : 4;

  // bijective XCD swizzle: 32 tiles of one image land on one XCD (nwg % 8 == 0)
  const int lin = blockIdx.x + (blockIdx.y << 4) + (blockIdx.z << 5);
  const int cpx = (int)(gridDim.z << 2);            // nwg/8 = 4*NB
  const int wg = (lin & 7) * cpx + (lin >> 3);
  const int bl = wg >> 5, rem = wg & 31;
  const int o0 = (rem >> 4) << 8, n0 = (rem & 15) << 8;
  const int bg = b_base + bl;
  const int wm = w >> 2, wn = w & 3;

  if constexpr (L == 1) {
    for (int e = tid; e < 1536; e += 512) rgbWl[e] = rin(rgbW, e, bf);
  }
  const u16* xg = (const u16*)((const char*)outb +
                  (98304 + (size_t)(b_base >> 2) * 8388608) * esz);

  // fragment-read swizzle: logical chunk c at row r lives at phys chunk c^(r&7)
  const int q = lane >> 4, m15 = lane & 15;
  const int lro = m15 * 64 + ((q ^ (lane & 7)) * 8);   // u16 offset, kk=0; kk=1 => ^32
  // staging source swizzle (linear LDS dest: lane writes row lane>>3, phys chunk lane&7)
  const int srow8 = lane >> 3, schunk = (lane & 7) ^ srow8;
  const size_t aAst = (size_t)(o0 + srow8) * 512 + schunk * 8;

  const int ka0 = (w < 4) ? (2 * w) : (16 + 2 * (w - 4));  // A-early pair base
  const int ka1 = ka0 + 8;                                  // A-late pair base
  const int kbe = (w & 3) * 8 + (w >> 2) * 2;               // B-even pair base
  const int kb0 = kbe, kb1 = kbe + 1, kb2 = kbe + 4, kb3 = kbe + 5;
  size_t pB[4]; int oyv[4], oxv[4];
  {
    const int kk4[4] = {kb0, kb1, kb2, kb3};
#pragma unroll
    for (int j = 0; j < 4; ++j) {
      const int p = n0 + kk4[j] * 8 + srow8;
      const int oy = p >> 6, ox = p & 63;
      oyv[j] = oy; oxv[j] = ox;
      pB[j] = ((size_t)bl * 4356 + oy * 66 + ox) * 512 + schunk * 8;
    }
  }

#define STAGE_A(k_, aoff_) \
  async16(Wp + (aoff_) + (size_t)(k_) * 4096, &lds[nbb + (k_) * 512])
#define STAGE_B(j_, k_, sb_, ty1_, tx1_, ko_) do {                                   \
    if constexpr (L == 0) {                                                          \
      const int iy_ = oyv[j_] + (ty1_), ix_ = oxv[j_] + (tx1_);                      \
      const u16* s_ = (((unsigned)iy_ < 64u) & ((unsigned)ix_ < 64u))                \
        ? (xg + ((size_t)((bl << 12) + (iy_ << 6) + ix_) * 512 + (ko_) + schunk * 8))\
        : (zbuf + schunk * 8);                                                       \
      async16(s_, &lds[nbb + 16384 + (k_) * 512]);                                   \
    } else {                                                                         \
      async16(actBp + pB[j_] + (size_t)(sb_), &lds[nbb + 16384 + (k_) * 512]);       \
    } } while (0)

  f32x4 acc[8][4] = {};
  {  // prologue: stage K-step 0 into buffer 0 (t=0, ko=0)
    const int nbb = 0;
    const size_t aoff = aAst;
    STAGE_A(ka0, aoff); STAGE_A(ka0 + 1, aoff);
    STAGE_A(ka1, aoff); STAGE_A(ka1 + 1, aoff);
    STAGE_B(0, kb0, 0, -1, -1, 0);
    STAGE_B(1, kb1, 0, -1, -1, 0);
    STAGE_B(2, kb2, 0, -1, -1, 0);
    STAGE_B(3, kb3, 0, -1, -1, 0);
  }
  asm volatile("s_waitcnt vmcnt(0)" ::: "memory");
  __builtin_amdgcn_s_barrier();

  bf16x8 afr[4][2], bfA[2][2], bfB[2][2];
#pragma unroll 1
  for (int s = 0; s < 72; ++s) {
    const int db = s & 1;
    const int dbb = db << 15, nbb = dbb ^ 32768;
    const int s1 = s + 1, ok = (s1 < 72);
    const int tn = s1 >> 3, kon = (s1 & 7) << 6;
    const int tyn = (tn * 11) >> 5, txn = tn - tyn * 3;
    const size_t aoffn = (size_t)tn * 262144 + kon + aAst;
    const int sbn = (tyn * 66 + txn) * 512 + kon;   // L1 halo tap offset
    const int ty1 = tyn - 1, tx1 = txn - 1;         // L0 bounds-checked tap
    const int abase = dbb + wm * 8192;
    const int bbase = dbb + 16384 + wn * 4096;

    // ---- phase 0: quadrant (qm0, qn0); prefetch A-early(s+1)
#pragma unroll
    for (int mi = 0; mi < 4; ++mi) {
      afr[mi][0] = *(const bf16x8*)&lds[abase + mi * 1024 + lro];
      afr[mi][1] = *(const bf16x8*)&lds[abase + mi * 1024 + (lro ^ 32)];
    }
#pragma unroll
    for (int ni = 0; ni < 2; ++ni) {
      bfA[ni][0] = *(const bf16x8*)&lds[bbase + ni * 1024 + lro];
      bfA[ni][1] = *(const bf16x8*)&lds[bbase + ni * 1024 + (lro ^ 32)];
    }
    if (ok) { STAGE_A(ka0, aoffn); STAGE_A(ka0 + 1, aoffn); }
    __builtin_amdgcn_s_setprio(1);
#pragma unroll
    for (int mi = 0; mi < 4; ++mi)
#pragma unroll
      for (int ni = 0; ni < 2; ++ni)
#pragma unroll
        for (int kk = 0; kk < 2; ++kk)
          acc[mi][ni] = __builtin_amdgcn_mfma_f32_16x16x32_bf16(
              afr[mi][kk], bfA[ni][kk], acc[mi][ni], 0, 0, 0);
    __builtin_amdgcn_s_setprio(0);
    if (ok) { asm volatile("s_waitcnt vmcnt(4)" ::: "memory"); }
    else    { asm volatile("s_waitcnt vmcnt(2)" ::: "memory"); }
    __builtin_amdgcn_s_barrier();

    // ---- phase 1: quadrant (qm0, qn1); prefetch B-even(s+1)
#pragma unroll
    for (int ni = 0; ni < 2; ++ni) {
      bfB[ni][0] = *(const bf16x8*)&lds[bbase + 2048 + ni * 1024 + lro];
      bfB[ni][1] = *(const bf16x8*)&lds[bbase + 2048 + ni * 1024 + (lro ^ 32)];
    }
    if (ok) { STAGE_B(0, kb0, sbn, ty1, tx1, kon); STAGE_B(1, kb1, sbn, ty1, tx1, kon); }
    __builtin_amdgcn_s_setprio(1);
#pragma unroll
    for (int mi = 0; mi < 4; ++mi)
#pragma unroll
      for (int ni = 0; ni < 2; ++ni)
#pragma unroll
        for (int kk = 0; kk < 2; ++kk)
          acc[mi][2 + ni] = __builtin_amdgcn_mfma_f32_16x16x32_bf16(
              afr[mi][kk], bfB[ni][kk], acc[mi][2 + ni], 0, 0, 0);
    __builtin_amdgcn_s_setprio(0);
    if (ok) { asm volatile("s_waitcnt vmcnt(4)" ::: "memory"); }
    else    { asm volatile("s_waitcnt vmcnt(0)" ::: "memory"); }
    __builtin_amdgcn_s_barrier();

    // ---- phase 2: quadrant (qm1, qn0); prefetch B-odd(s+1); no barrier needed
#pragma unroll
    for (int mi = 0; mi < 4; ++mi) {
      afr[mi][0] = *(const bf16x8*)&lds[abase + 4096 + mi * 1024 + lro];
      afr[mi][1] = *(const bf16x8*)&lds[abase + 4096 + mi * 1024 + (lro ^ 32)];
    }
    if (ok) { STAGE_B(2, kb2, sbn, ty1, tx1, kon); STAGE_B(3, kb3, sbn, ty1, tx1, kon); }
    __builtin_amdgcn_s_setprio(1);
#pragma unroll
    for (int mi = 0; mi < 4; ++mi)
#pragma unroll
      for (int ni = 0; ni < 2; ++ni)
#pragma unroll
        for (int kk = 0; kk < 2; ++kk)
          acc[4 + mi][ni] = __builtin_amdgcn_mfma_f32_16x16x32_bf16(
              afr[mi][kk], bfA[ni][kk], acc[4 + mi][ni], 0, 0, 0);
    __builtin_amdgcn_s_setprio(0);

    // ---- phase 3: quadrant (qm1, qn1); prefetch A-late(s+1)
    if (ok) { STAGE_A(ka1, aoffn); STAGE_A(ka1 + 1, aoffn); }
    __builtin_amdgcn_s_setprio(1);
#pragma unroll
    for (int mi = 0; mi < 4; ++mi)
#pragma unroll
      for (int ni = 0; ni < 2; ++ni)
#pragma unroll
        for (int kk = 0; kk < 2; ++kk)
          acc[4 + mi][2 + ni] = __builtin_amdgcn_mfma_f32_16x16x32_bf16(
              afr[mi][kk], bfB[ni][kk], acc[4 + mi][2 + ni], 0, 0, 0);
    __builtin_amdgcn_s_setprio(0);
    asm volatile("s_waitcnt vmcnt(4)" ::: "memory");
    __builtin_amdgcn_s_barrier();
  }
#undef STAGE_A
#undef STAGE_B

  if constexpr (L == 0) {
    // epilogue: lrelu(acc*dm + b + ns*noise)*s1 -> actB halo NHWC [bl][66][66][512]
#pragma unroll
    for (int ai = 0; ai < 8; ++ai) {
      const int o = o0 + wm * 128 + ai * 16 + q * 4;
      const f32x4 dv = *(const f32x4*)&dmod[bg * 512 + o];
      const f32x4 sv = *(const f32x4*)&saux[bg * 512 + o];
      float bv[4], nv[4];
#pragma unroll
      for (int r = 0; r < 4; ++r) { bv[r] = rin(bias, o + r, bf); nv[r] = rin(nsc, o + r, bf); }
#pragma unroll
      for (int bj = 0; bj < 4; ++bj) {
        const int p = n0 + wn * 64 + bj * 16 + m15;
        const float np = rin(noise, (size_t)bg * 4096 + p, bf);
        u16x4 pack;
#pragma unroll
        for (int r = 0; r < 4; ++r) {
          float v = acc[ai][bj][r] * dv[r] + bv[r] + nv[r] * np;
          v = (v >= 0.f) ? v : 0.2f * v;
          pack[r] = f2b(v * sv[r]);
        }
        const int oy = p >> 6, ox = p & 63;
        *(u16x4*)&actBp[((size_t)(bl * 4356) + (oy + 1) * 66 + (ox + 1)) * 512 + o] = pack;
      }
    }
  } else {
    // epilogue: x = lrelu(...) -> d_out x-region (dual dtype, NCHW);
    // rgb partials: atomicAdd rgbacc[b][c][p] += sum_o rgbW[c][o]*(x*sR)[o]
    char* xreg = (char*)outb + 98304 * esz;
    float racc[4][3] = {};
#pragma unroll
    for (int ai = 0; ai < 8; ++ai) {
      const int o = o0 + wm * 128 + ai * 16 + q * 4;
      const f32x4 dv = *(const f32x4*)&dmod[bg * 512 + o];
      const f32x4 srv = *(const f32x4*)&saux[bg * 512 + o];
      float bv[4], nv[4], w0l[4], w1l[4], w2l[4];
#pragma unroll
      for (int r = 0; r < 4; ++r) {
        bv[r] = rin(bias, o + r, bf); nv[r] = rin(nsc, o + r, bf);
        w0l[r] = rgbWl[o + r]; w1l[r] = rgbWl[512 + o + r]; w2l[r] = rgbWl[1024 + o + r];
      }
#pragma unroll
      for (int bj = 0; bj < 4; ++bj) {
        const int p = n0 + wn * 64 + bj * 16 + m15;
        const float np = rin(noise, (size_t)bg * 4096 + p, bf);
#pragma unroll
        for (int r = 0; r < 4; ++r) {
          float v = acc[ai][bj][r] * dv[r] + bv[r] + nv[r] * np;
          v = (v >= 0.f) ? v : 0.2f * v;
          const size_t xi = (size_t)(bg * 512 + o + r) * 4096 + p;
          if (bf) ((u16*)xreg)[xi] = f2b(v); else ((float*)xreg)[xi] = v;
          const float xr = v * srv[r];
          racc[bj][0] += w0l[r] * xr;
          racc[bj][1] += w1l[r] * xr;
          racc[bj][2] += w2l[r] * xr;
        }
      }
    }
#pragma unroll
    for (int bj = 0; bj < 4; ++bj) {
      const int p = n0 + wn * 64 + bj * 16 + m15;
#pragma unroll
      for (int c = 0; c < 3; ++c) {
        float t = racc[bj][c];
        t += __shfl_xor(t, 16, 64);
        t += __shfl_xor(t, 32, 64);
        if (lane < 16) atomicAdd(&rgbacc[(size_t)(bg * 3 + c) * 4096 + p], t);
      }
    }
  }
}

// ---- finalize rgb: out[b,c,p] = up2(rgb) + rgbB[c] + rgbacc[b,c,p]
__global__ void rgbfin_kernel(const float* __restrict__ rgbacc, const void* __restrict__ rgbB,
                              const void* __restrict__ rgb, void* __restrict__ outb,
                              const unsigned* __restrict__ w0raw) {
  __shared__ int shflag;
  const int tid = threadIdx.x;
  const int bf = detect_bf(w0raw, tid, &shflag);
  const int g = blockIdx.x * 256 + tid;  // 0..32767
  const int b = g >> 12, p = g & 4095;
  const int oy = p >> 6, ox = p & 63;
  const int m = oy >> 1; int iy0, iy1; float wy0, wy1;
  if ((oy & 1) == 0) { iy0 = (m > 0) ? m - 1 : 0; iy1 = m; wy0 = 0.25f; wy1 = 0.75f; }
  else               { iy0 = m; iy1 = (m < 31) ? m + 1 : 31; wy0 = 0.75f; wy1 = 0.25f; }
  const int mx = ox >> 1; int ix0, ix1; float wx0, wx1;
  if ((ox & 1) == 0) { ix0 = (mx > 0) ? mx - 1 : 0; ix1 = mx; wx0 = 0.25f; wx1 = 0.75f; }
  else               { ix0 = mx; ix1 = (mx < 31) ? mx + 1 : 31; wx0 = 0.75f; wx1 = 0.25f; }
#pragma unroll
  for (int c = 0; c < 3; ++c) {
    const size_t rb = (size_t)(b * 3 + c) * 1024;
    const float up = wy0 * (wx0 * rin(rgb, rb + iy0 * 32 + ix0, bf) + wx1 * rin(rgb, rb + iy0 * 32 + ix1, bf))
                   + wy1 * (wx0 * rin(rgb, rb + iy1 * 32 + ix0, bf) + wx1 * rin(rgb, rb + iy1 * 32 + ix1, bf));
    const float v = up + rin(rgbB, c, bf) + rgbacc[(size_t)(b * 3 + c) * 4096 + p];
    const size_t oi = ((size_t)(b * 3 + c) << 12) + p;
    if (bf) ((u16*)outb)[oi] = f2b(v); else ((float*)outb)[oi] = v;
  }
}

// ---------------- workspace layout (bytes) ----------------
// s0:1024  s1:17408  sR:33792  dm0:50176  dm1:66560
// zbuf:82944 (4096, zeroed)  rgbacc:87040 (393216)  -> 480256
// Wp0:480256 (4718592)  Wp1:5198848 (4718592)
// actB:9917440 (NB=8: 35684352 -> end 45.6MB; NB=4 fallback -> 27.8MB)

extern "C" void kernel_launch(void* const* d_in, const int* in_sizes, int n_in,
                              void* d_out, int out_size, void* d_ws, size_t ws_size,
                              hipStream_t stream) {
  const void* maps   = d_in[0];
  const void* wlat   = d_in[1];
  const void* rgb    = d_in[2];
  const void* noise0 = d_in[3];
  const void* noise1 = d_in[4];
  const void* w0     = d_in[5];
  const void* b0     = d_in[6];
  const void* sW0    = d_in[7];
  const void* sB0    = d_in[8];
  const void* ns0    = d_in[9];
  const void* w1     = d_in[10];
  const void* b1     = d_in[11];
  const void* sW1    = d_in[12];
  const void* sB1    = d_in[13];
  const void* ns1    = d_in[14];
  const void* rgbW   = d_in[15];
  const void* rgbB   = d_in[16];
  const void* rgbSW  = d_in[17];
  const void* rgbSB  = d_in[18];
  const unsigned* w0raw = (const unsigned*)w0;

  char* ws = (char*)d_ws;
  float* s0     = (float*)(ws + 1024);
  float* s1     = (float*)(ws + 17408);
  float* sR     = (float*)(ws + 33792);
  float* dm0    = (float*)(ws + 50176);
  float* dm1    = (float*)(ws + 66560);
  u16*   zbuf   = (u16*)(ws + 82944);
  float* rgbacc = (float*)(ws + 87040);
  u16*   Wp0    = (u16*)(ws + 480256);
  u16*   Wp1    = (u16*)(ws + 5198848);
  u16*   actB   = (u16*)(ws + 9917440);

  // full-batch conv launches (best occupancy) if actB for 8 batches fits in ws
  const bool full = ws_size >= (size_t)(9917440 + 35684352);
  const int NB = full ? 8 : 4;

  styleall_kernel<<<dim3(8, 8, 3), 256, 0, stream>>>(wlat, sW0, sB0, sW1, sB1, rgbSW, rgbSB,
                                                     s0, s1, sR, w0raw);
  demod_kernel<<<dim3(512, 2), 256, 0, stream>>>(w0, w1, s0, s1, dm0, dm1, Wp0, Wp1, w0raw);
  prep_kernel<<<NB * 65 + 97, 256, 0, stream>>>(actB, (u32x4*)zbuf, NB);

  for (int pass = 0; pass < 8 / NB; ++pass) {
    const int b_base = pass * NB;
    upsample_kernel<<<dim3(64, 16, NB), 256, 0, stream>>>(maps, s0, d_out, b_base, w0raw);
    conv_kernel<0><<<dim3(16, 2, NB), 512, 0, stream>>>(d_out, actB, Wp0, dm0,
        b0, ns0, noise0, s1, zbuf, nullptr, nullptr, b_base, w0raw);
    conv_kernel<1><<<dim3(16, 2, NB), 512, 0, stream>>>(d_out, actB, Wp1, dm1,
        b1, ns1, noise1, sR, zbuf, rgbW, rgbacc, b_base, w0raw);
  }
  rgbfin_kernel<<<128, 256, 0, stream>>>(rgbacc, rgbB, rgb, d_out, w0raw);
}

// Round 2
// 450.987 us; speedup vs baseline: 1.1135x; 1.0023x over previous
//
#include <hip/hip_runtime.h>

typedef unsigned short u16;
typedef short bf16x8 __attribute__((ext_vector_type(8)));
typedef float f32x4 __attribute__((ext_vector_type(4)));
typedef u16 u16x4 __attribute__((ext_vector_type(4)));
typedef u16 u16x8 __attribute__((ext_vector_type(8)));
typedef unsigned u32x4 __attribute__((ext_vector_type(4)));

__device__ __forceinline__ float b2f(u16 v) {
  union { unsigned u; float f; } x; x.u = ((unsigned)v) << 16; return x.f;
}
__device__ __forceinline__ u16 f2b(float f) {
  unsigned u = __float_as_uint(f);
  unsigned r = (u + 0x7FFFu + ((u >> 16) & 1u)) >> 16;
  return (u16)r;
}
// dtype-agnostic input read: bf==1 -> bf16, bf==0 -> f32
__device__ __forceinline__ float rin(const void* p, size_t i, int bf) {
  return bf ? b2f(((const u16*)p)[i]) : ((const float*)p)[i];
}
__device__ __forceinline__ void async16(const void* g, void* l) {
  __builtin_amdgcn_global_load_lds((const __attribute__((address_space(1))) unsigned*)g,
                                   (__attribute__((address_space(3))) unsigned*)l, 16, 0, 0);
}
// per-block dtype detection: wave 0 inspects w0's first 64 words (L2-resident),
// broadcasts via LDS. bf16 data -> every low-u16 has plausible small-bf16 exponent.
__device__ __forceinline__ int detect_bf(const unsigned* __restrict__ w0raw, int tid, int* shflag) {
  if (tid < 64) {
    const unsigned lo = w0raw[tid] & 0xFFFFu;
    const unsigned e = (lo >> 7) & 0xFFu;
    const unsigned long long bad = __ballot(e < 100u || e > 126u);
    if (tid == 0) *shflag = (bad == 0ull) ? 1 : 0;
  }
  __syncthreads();
  return *shflag;
}

// ---- all three style GEMMs in one launch: s[b,i] = sum_z w[b,z]*sW[i,z] + sB[i]
__global__ void styleall_kernel(const void* __restrict__ w,
                                const void* __restrict__ sW0, const void* __restrict__ sB0,
                                const void* __restrict__ sW1, const void* __restrict__ sB1,
                                const void* __restrict__ sWR, const void* __restrict__ sBR,
                                float* __restrict__ s0, float* __restrict__ s1,
                                float* __restrict__ sR, const unsigned* __restrict__ w0raw) {
  __shared__ int shflag;
  const int tid = threadIdx.x;
  const int bf = detect_bf(w0raw, tid, &shflag);
  const int mat = blockIdx.z, b = blockIdx.y, oc = blockIdx.x;
  const void* sW = (mat == 0) ? sW0 : ((mat == 1) ? sW1 : sWR);
  const void* sB = (mat == 0) ? sB0 : ((mat == 1) ? sB1 : sBR);
  float* out = (mat == 0) ? s0 : ((mat == 1) ? s1 : sR);
  const int i = oc * 64 + (tid >> 2), q = tid & 3;
  float acc = 0.f;
  if (bf) {
    const u16* rp = (const u16*)sW + (size_t)i * 512 + q * 128;
    const u16* wp = (const u16*)w + b * 512 + q * 128;
    for (int z = 0; z < 128; z += 8) {
      u16x8 a = *(const u16x8*)(rp + z), c = *(const u16x8*)(wp + z);
#pragma unroll
      for (int j = 0; j < 8; ++j) acc += b2f(a[j]) * b2f(c[j]);
    }
  } else {
    const float* rp = (const float*)sW + (size_t)i * 512 + q * 128;
    const float* wp = (const float*)w + b * 512 + q * 128;
    for (int z = 0; z < 128; z += 4) {
      f32x4 a = *(const f32x4*)(rp + z), c = *(const f32x4*)(wp + z);
#pragma unroll
      for (int j = 0; j < 4; ++j) acc += a[j] * c[j];
    }
  }
  acc += __shfl_xor(acc, 1, 64);
  acc += __shfl_xor(acc, 2, 64);
  if (q == 0) out[b * 512 + i] = acc + rin(sB, i, bf);
}

// ---- demod (both layers in one launch, coalesced): block (o, layer).
__global__ void demod_kernel(const void* __restrict__ W0, const void* __restrict__ W1,
                             const float* __restrict__ s0, const float* __restrict__ s1,
                             float* __restrict__ dm0, float* __restrict__ dm1,
                             u16* __restrict__ Wp0, u16* __restrict__ Wp1,
                             const unsigned* __restrict__ w0raw) {
  __shared__ int shflag;
  __shared__ float wl[4608];
  __shared__ float wsq[512];
  const int tid = threadIdx.x, lane = tid & 63, wv = tid >> 6;
  const int bf = detect_bf(w0raw, tid, &shflag);
  const int o = blockIdx.x, layer = blockIdx.y;
  const void* W = layer ? W1 : W0;
  const float* s = layer ? s1 : s0;
  float* d = layer ? dm1 : dm0;
  u16* Wp = layer ? Wp1 : Wp0;

  if (bf) {
    const u16* src = (const u16*)W + (size_t)o * 4608;
    for (int e = tid; e < 576; e += 256) {
      u16x8 v = *(const u16x8*)(src + e * 8);
#pragma unroll
      for (int j = 0; j < 8; ++j) wl[e * 8 + j] = b2f(v[j]);
    }
  } else {
    const float* src = (const float*)W + (size_t)o * 4608;
    for (int e = tid; e < 1152; e += 256) {
      f32x4 v = *(const f32x4*)(src + e * 4);
#pragma unroll
      for (int j = 0; j < 4; ++j) wl[e * 4 + j] = v[j];
    }
  }
  __syncthreads();
  for (int i = tid; i < 512; i += 256) {
    float ss = 0.f;
#pragma unroll
    for (int t = 0; t < 9; ++t) {
      const float f = wl[i * 9 + t];
      ss += f * f;
      Wp[t * 262144 + o * 512 + i] = f2b(f);
    }
    wsq[i] = ss;
  }
  __syncthreads();
#pragma unroll
  for (int bb = 0; bb < 2; ++bb) {
    const int b = wv * 2 + bb;
    float part = 0.f;
    for (int i = lane; i < 512; i += 64) { const float sv = s[b * 512 + i]; part += wsq[i] * sv * sv; }
#pragma unroll
    for (int st = 1; st < 64; st <<= 1) part += __shfl_xor(part, st, 64);
    if (lane == 0) d[b * 512 + o] = rsqrtf(part + 1e-8f);
  }
}

// ---- prep: zero actB's halo ring only (interior is overwritten by conv0) + zbuf/rgbacc
__global__ void prep_kernel(u16* __restrict__ actB, u32x4* __restrict__ zr, int NB) {
  const int id = blockIdx.x, tid = threadIdx.x;
  if (id < NB * 65) {
    const int bl = id / 65, sub = id - bl * 65;
    const int c = sub * 256 + tid;      // 0..16639 : 260 ring px x 64 chunks
    const int px = c >> 6, seg = c & 63;
    int oy, ox;
    if (px < 66)       { oy = 0;  ox = px; }
    else if (px < 132) { oy = 65; ox = px - 66; }
    else { const int e = px - 132; oy = 1 + (e >> 1); ox = (e & 1) * 65; }
    u32x4 z = {0, 0, 0, 0};
    *(u32x4*)&actB[((size_t)(bl * 4356) + oy * 66 + ox) * 512 + seg * 8] = z;
  } else {
    const int c = (id - NB * 65) * 256 + tid;
    if (c < 24832) { u32x4 z = {0, 0, 0, 0}; zr[c] = z; }
  }
}

// ---- bilinear 2x upsample * s0 -> bf16 NHWC scratch [bl][4096][512] inside d_out x-region
// block->image mapping is XCD-aligned (bl = id&7) so conv0's B reads hit the local L2.
__global__ void upsample_kernel(const void* __restrict__ maps, const float* __restrict__ s,
                                void* __restrict__ outb, int b_base,
                                const unsigned* __restrict__ w0raw) {
  __shared__ int shflag;
  __shared__ float it[32][2][33];
  const int tid = threadIdx.x;
  const int bf = detect_bf(w0raw, tid, &shflag);
  const size_t esz = bf ? 2 : 4;
  u16* xg = (u16*)((char*)outb + (98304 + (size_t)(b_base >> 2) * 8388608) * esz);
  int oy, i0, bl;
  if (gridDim.z == 8) {
    const int id = blockIdx.x + (blockIdx.y << 6) + (blockIdx.z << 10);
    bl = id & 7; const int r = id >> 3; oy = r & 63; i0 = (r >> 6) << 5;
  } else {
    oy = blockIdx.x; i0 = blockIdx.y << 5; bl = blockIdx.z;
  }
  const int bg = b_base + bl;
  const int m = oy >> 1;
  int iy0, iy1; float wy0, wy1;
  if ((oy & 1) == 0) { iy0 = (m > 0) ? m - 1 : 0; iy1 = m; wy0 = 0.25f; wy1 = 0.75f; }
  else               { iy0 = m; iy1 = (m < 31) ? m + 1 : 31; wy0 = 0.75f; wy1 = 0.25f; }
#pragma unroll
  for (int k = 0; k < 8; ++k) {
    const int e = tid + k * 256;  // 32c x 2rows x 32x = 2048
    const int c = e >> 6, wsel = (e >> 5) & 1, x = e & 31;
    const int iy = wsel ? iy1 : iy0;
    it[c][wsel][x] = rin(maps, ((size_t)(bg * 512 + i0 + c) * 32 + iy) * 32 + x, bf);
  }
  __syncthreads();
#pragma unroll
  for (int k = 0; k < 8; ++k) {
    const int e = tid + k * 256;  // 64 xx * 32 c = 2048
    const int xx = e >> 5, c = e & 31;
    const int mx = xx >> 1;
    int ix0, ix1; float wx0, wx1;
    if ((xx & 1) == 0) { ix0 = (mx > 0) ? mx - 1 : 0; ix1 = mx; wx0 = 0.25f; wx1 = 0.75f; }
    else               { ix0 = mx; ix1 = (mx < 31) ? mx + 1 : 31; wx0 = 0.75f; wx1 = 0.25f; }
    const float r0 = wx0 * it[c][0][ix0] + wx1 * it[c][0][ix1];
    const float r1 = wx0 * it[c][1][ix0] + wx1 * it[c][1][ix1];
    const float v = (wy0 * r0 + wy1 * r1) * s[bg * 512 + i0 + c];
    xg[((size_t)(bl * 4096) + oy * 64 + xx) * 512 + i0 + c] = f2b(v);
  }
}

// ---- conv (both layers): 256x256 implicit-GEMM tile, BK=64, 8 waves (2Mx4N),
// m201-style phase discipline: {ds_reads | stage-issue} -> barrier -> lgkmcnt(0)
// -> setprio(1) MFMA cluster setprio(0) -> counted vmcnt -> barrier.
// Counted-vmcnt ledger (per wave, in-order retire), stages prefetch step s+1:
//   ph0 issues A-early(s+1); end-ph0 vmcnt(4) retires B-odd(s)
//   ph1 issues B-even(s+1); end-ph1 vmcnt(4) retires A-late(s)
//   ph2 issues B-odd(s+1);  ph3 issues A-late(s+1)
//   end-ph3 vmcnt(4) retires A-early(s+1)+B-even(s+1)  (never 0 in steady state)
// All LDS read bases are loop-carried (XOR 32768/step) so ds_read offsets fold
// to immediates; stage sources advance +64/step with tap recompute every 8 steps.
template <int L>
__global__ __launch_bounds__(512, 2) void conv_kernel(
    void* __restrict__ outb, u16* __restrict__ actBp,
    const u16* __restrict__ Wp, const float* __restrict__ dmod,
    const void* __restrict__ bias, const void* __restrict__ nsc,
    const void* __restrict__ noise, const float* __restrict__ saux,
    const u16* __restrict__ zbuf, const void* __restrict__ rgbW,
    float* __restrict__ rgbacc, int b_base,
    const unsigned* __restrict__ w0raw) {
  __shared__ __attribute__((aligned(16))) u16 lds[65536];  // [2 dbuf][A 16K u16 | B 16K u16]
  __shared__ float rgbWl[L == 1 ? 1536 : 4];
  __shared__ int shflag;
  const int tid = threadIdx.x, lane = tid & 63, w = tid >> 6;
  const int bf = detect_bf(w0raw, tid, &shflag);
  const size_t esz = bf ? 2 : 4;

  // bijective XCD swizzle: 32 tiles of one image land on one XCD (nwg % 8 == 0)
  const int lin = blockIdx.x + (blockIdx.y << 4) + (blockIdx.z << 5);
  const int cpx = (int)(gridDim.z << 2);            // nwg/8 = 4*NB
  const int wg = (lin & 7) * cpx + (lin >> 3);
  const int bl = wg >> 5, rem = wg & 31;
  const int o0 = (rem >> 4) << 8, n0 = (rem & 15) << 8;
  const int bg = b_base + bl;
  const int wm = w >> 2, wn = w & 3;

  if constexpr (L == 1) {
    for (int e = tid; e < 1536; e += 512) rgbWl[e] = rin(rgbW, e, bf);
  }
  const u16* xg = (const u16*)((const char*)outb +
                  (98304 + (size_t)(b_base >> 2) * 8388608) * esz);

  // fragment-read swizzle: logical chunk c at row r lives at phys chunk c^(r&7)
  const int q = lane >> 4, m15 = lane & 15;
  const int lro = m15 * 64 + ((q ^ (lane & 7)) * 8);   // u16 offset, kk=0; kk=1 => ^32
  // staging source swizzle (linear LDS dest: lane writes row lane>>3, phys chunk lane&7)
  const int srow8 = lane >> 3, schunk = (lane & 7) ^ srow8;
  const size_t aAst = (size_t)(o0 + srow8) * 512 + schunk * 8;

  const int ka0 = (w < 4) ? (2 * w) : (16 + 2 * (w - 4));  // A-early pair base
  const int ka1 = ka0 + 8;                                  // A-late pair base
  const int kbe = (w & 3) * 8 + (w >> 2) * 2;               // B-even pair base
  const int kb0 = kbe, kb1 = kbe + 1, kb2 = kbe + 4, kb3 = kbe + 5;
  int oyv[4], oxv[4];
  size_t pB[4];
  {
    const int kk4[4] = {kb0, kb1, kb2, kb3};
#pragma unroll
    for (int j = 0; j < 4; ++j) {
      const int p = n0 + kk4[j] * 8 + srow8;
      const int oy = p >> 6, ox = p & 63;
      oyv[j] = oy; oxv[j] = ox;
      pB[j] = ((size_t)bl * 4356 + oy * 66 + ox) * 512 + schunk * 8;
    }
  }

  // loop-carried staging state
  const u16* bBase[4];
  int koff, aoffu;
  auto setTap = [&](int tn_) {
    const int ty_ = (tn_ * 11) >> 5, tx_ = tn_ - ty_ * 3;
    koff = 0;
    aoffu = tn_ * 262144;
    if constexpr (L == 0) {
#pragma unroll
      for (int j = 0; j < 4; ++j) {
        const int iy_ = oyv[j] + ty_ - 1, ix_ = oxv[j] + tx_ - 1;
        bBase[j] = (((unsigned)iy_ < 64u) & ((unsigned)ix_ < 64u))
          ? (xg + ((size_t)((bl << 12) + (iy_ << 6) + ix_) * 512 + schunk * 8))
          : (zbuf + schunk * 8);
      }
    } else {
      const int sb_ = (ty_ * 66 + tx_) * 512;
#pragma unroll
      for (int j = 0; j < 4; ++j) bBase[j] = actBp + pB[j] + sb_;
    }
  };

#define STAGE_A(k_) \
  async16(Wp + aAst + (size_t)aoffu + (size_t)(k_) * 4096, &lds[stb + (k_) * 512])
#define STAGE_B(j_, k_) \
  async16(bBase[j_] + koff, &lds[stb + 16384 + (k_) * 512])

  f32x4 acc[8][4] = {};
  {  // prologue: stage K-step 0 into buffer 0 (t=0, ko=0)
    setTap(0);
    const int stb = 0;
    STAGE_A(ka0); STAGE_A(ka0 + 1);
    STAGE_A(ka1); STAGE_A(ka1 + 1);
    STAGE_B(0, kb0); STAGE_B(1, kb1);
    STAGE_B(2, kb2); STAGE_B(3, kb3);
  }
  koff = 64; aoffu = 64;   // state for s1 = 1 (tap 0, kon 64)
  asm volatile("s_waitcnt vmcnt(0)" ::: "memory");
  __builtin_amdgcn_s_barrier();

  // carried LDS read bases (include dbuf bit; XOR 32768 per step)
  int arA  = wm * 8192 + lro;
  int arAx = wm * 8192 + (lro ^ 32);
  int arB  = 16384 + wn * 4096 + lro;
  int arBx = 16384 + wn * 4096 + (lro ^ 32);
  int stb  = 32768;   // stage target buffer (for step s+1)

  bf16x8 afr[4][2], bfA[2][2], bfB[2][2];
#pragma unroll 1
  for (int s = 0; s < 72; ++s) {
    const int s1 = s + 1, ok = (s1 < 72);
    if (ok && (s1 & 7) == 0) setTap(s1 >> 3);

    // ---------- phase 0: quadrant (A-early, B-even); prefetch A-early(s+1)
#pragma unroll
    for (int mi = 0; mi < 4; ++mi) {
      afr[mi][0] = *(const bf16x8*)&lds[arA + mi * 1024];
      afr[mi][1] = *(const bf16x8*)&lds[arAx + mi * 1024];
    }
#pragma unroll
    for (int ni = 0; ni < 2; ++ni) {
      bfA[ni][0] = *(const bf16x8*)&lds[arB + ni * 1024];
      bfA[ni][1] = *(const bf16x8*)&lds[arBx + ni * 1024];
    }
    if (ok) { STAGE_A(ka0); STAGE_A(ka0 + 1); }
    __builtin_amdgcn_s_barrier();
    asm volatile("s_waitcnt lgkmcnt(0)" ::: "memory");
    __builtin_amdgcn_sched_barrier(0);
    __builtin_amdgcn_s_setprio(1);
#pragma unroll
    for (int mi = 0; mi < 4; ++mi)
#pragma unroll
      for (int ni = 0; ni < 2; ++ni)
#pragma unroll
        for (int kk = 0; kk < 2; ++kk)
          acc[mi][ni] = __builtin_amdgcn_mfma_f32_16x16x32_bf16(
              afr[mi][kk], bfA[ni][kk], acc[mi][ni], 0, 0, 0);
    __builtin_amdgcn_s_setprio(0);
    if (ok) { asm volatile("s_waitcnt vmcnt(4)" ::: "memory"); }
    else    { asm volatile("s_waitcnt vmcnt(2)" ::: "memory"); }
    __builtin_amdgcn_s_barrier();

    // ---------- phase 1: quadrant (A-early, B-odd); prefetch B-even(s+1)
#pragma unroll
    for (int ni = 0; ni < 2; ++ni) {
      bfB[ni][0] = *(const bf16x8*)&lds[arB + 2048 + ni * 1024];
      bfB[ni][1] = *(const bf16x8*)&lds[arBx + 2048 + ni * 1024];
    }
    if (ok) { STAGE_B(0, kb0); STAGE_B(1, kb1); }
    __builtin_amdgcn_s_barrier();
    asm volatile("s_waitcnt lgkmcnt(0)" ::: "memory");
    __builtin_amdgcn_sched_barrier(0);
    __builtin_amdgcn_s_setprio(1);
#pragma unroll
    for (int mi = 0; mi < 4; ++mi)
#pragma unroll
      for (int ni = 0; ni < 2; ++ni)
#pragma unroll
        for (int kk = 0; kk < 2; ++kk)
          acc[mi][2 + ni] = __builtin_amdgcn_mfma_f32_16x16x32_bf16(
              afr[mi][kk], bfB[ni][kk], acc[mi][2 + ni], 0, 0, 0);
    __builtin_amdgcn_s_setprio(0);
    if (ok) { asm volatile("s_waitcnt vmcnt(4)" ::: "memory"); }
    else    { asm volatile("s_waitcnt vmcnt(0)" ::: "memory"); }
    __builtin_amdgcn_s_barrier();

    // ---------- phase 2: quadrant (A-late, B-even); prefetch B-odd(s+1)
#pragma unroll
    for (int mi = 0; mi < 4; ++mi) {
      afr[mi][0] = *(const bf16x8*)&lds[arA + 4096 + mi * 1024];
      afr[mi][1] = *(const bf16x8*)&lds[arAx + 4096 + mi * 1024];
    }
    if (ok) { STAGE_B(2, kb2); STAGE_B(3, kb3); }
    __builtin_amdgcn_s_barrier();
    asm volatile("s_waitcnt lgkmcnt(0)" ::: "memory");
    __builtin_amdgcn_sched_barrier(0);
    __builtin_amdgcn_s_setprio(1);
#pragma unroll
    for (int mi = 0; mi < 4; ++mi)
#pragma unroll
      for (int ni = 0; ni < 2; ++ni)
#pragma unroll
        for (int kk = 0; kk < 2; ++kk)
          acc[4 + mi][ni] = __builtin_amdgcn_mfma_f32_16x16x32_bf16(
              afr[mi][kk], bfA[ni][kk], acc[4 + mi][ni], 0, 0, 0);
    __builtin_amdgcn_s_setprio(0);
    // no trailing sync: phase 3 reads no LDS

    // ---------- phase 3: quadrant (A-late, B-odd); prefetch A-late(s+1)
    if (ok) { STAGE_A(ka1); STAGE_A(ka1 + 1); }
    __builtin_amdgcn_s_setprio(1);
#pragma unroll
    for (int mi = 0; mi < 4; ++mi)
#pragma unroll
      for (int ni = 0; ni < 2; ++ni)
#pragma unroll
        for (int kk = 0; kk < 2; ++kk)
          acc[4 + mi][2 + ni] = __builtin_amdgcn_mfma_f32_16x16x32_bf16(
              afr[mi][kk], bfB[ni][kk], acc[4 + mi][2 + ni], 0, 0, 0);
    __builtin_amdgcn_s_setprio(0);
    asm volatile("s_waitcnt vmcnt(4)" ::: "memory");
    __builtin_amdgcn_s_barrier();

    arA ^= 32768; arAx ^= 32768; arB ^= 32768; arBx ^= 32768; stb ^= 32768;
    koff += 64; aoffu += 64;
  }
#undef STAGE_A
#undef STAGE_B

  if constexpr (L == 0) {
    // epilogue: lrelu(acc*dm + b + ns*noise)*s1 -> actB halo NHWC [bl][66][66][512]
#pragma unroll
    for (int ai = 0; ai < 8; ++ai) {
      const int o = o0 + wm * 128 + ai * 16 + q * 4;
      const f32x4 dv = *(const f32x4*)&dmod[bg * 512 + o];
      const f32x4 sv = *(const f32x4*)&saux[bg * 512 + o];
      float bv[4], nv[4];
#pragma unroll
      for (int r = 0; r < 4; ++r) { bv[r] = rin(bias, o + r, bf); nv[r] = rin(nsc, o + r, bf); }
#pragma unroll
      for (int bj = 0; bj < 4; ++bj) {
        const int p = n0 + wn * 64 + bj * 16 + m15;
        const float np = rin(noise, (size_t)bg * 4096 + p, bf);
        u16x4 pack;
#pragma unroll
        for (int r = 0; r < 4; ++r) {
          float v = acc[ai][bj][r] * dv[r] + bv[r] + nv[r] * np;
          v = (v >= 0.f) ? v : 0.2f * v;
          pack[r] = f2b(v * sv[r]);
        }
        const int oy = p >> 6, ox = p & 63;
        *(u16x4*)&actBp[((size_t)(bl * 4356) + (oy + 1) * 66 + (ox + 1)) * 512 + o] = pack;
      }
    }
  } else {
    // epilogue: x = lrelu(...) -> d_out x-region (dual dtype, NCHW);
    // rgb partials: atomicAdd rgbacc[b][c][p] += sum_o rgbW[c][o]*(x*sR)[o]
    char* xreg = (char*)outb + 98304 * esz;
    float racc[4][3] = {};
#pragma unroll
    for (int ai = 0; ai < 8; ++ai) {
      const int o = o0 + wm * 128 + ai * 16 + q * 4;
      const f32x4 dv = *(const f32x4*)&dmod[bg * 512 + o];
      const f32x4 srv = *(const f32x4*)&saux[bg * 512 + o];
      float bv[4], nv[4], w0l[4], w1l[4], w2l[4];
#pragma unroll
      for (int r = 0; r < 4; ++r) {
        bv[r] = rin(bias, o + r, bf); nv[r] = rin(nsc, o + r, bf);
        w0l[r] = rgbWl[o + r]; w1l[r] = rgbWl[512 + o + r]; w2l[r] = rgbWl[1024 + o + r];
      }
#pragma unroll
      for (int bj = 0; bj < 4; ++bj) {
        const int p = n0 + wn * 64 + bj * 16 + m15;
        const float np = rin(noise, (size_t)bg * 4096 + p, bf);
#pragma unroll
        for (int r = 0; r < 4; ++r) {
          float v = acc[ai][bj][r] * dv[r] + bv[r] + nv[r] * np;
          v = (v >= 0.f) ? v : 0.2f * v;
          const size_t xi = (size_t)(bg * 512 + o + r) * 4096 + p;
          if (bf) ((u16*)xreg)[xi] = f2b(v); else ((float*)xreg)[xi] = v;
          const float xr = v * srv[r];
          racc[bj][0] += w0l[r] * xr;
          racc[bj][1] += w1l[r] * xr;
          racc[bj][2] += w2l[r] * xr;
        }
      }
    }
#pragma unroll
    for (int bj = 0; bj < 4; ++bj) {
      const int p = n0 + wn * 64 + bj * 16 + m15;
#pragma unroll
      for (int c = 0; c < 3; ++c) {
        float t = racc[bj][c];
        t += __shfl_xor(t, 16, 64);
        t += __shfl_xor(t, 32, 64);
        if (lane < 16) atomicAdd(&rgbacc[(size_t)(bg * 3 + c) * 4096 + p], t);
      }
    }
  }
}

// ---- finalize rgb: out[b,c,p] = up2(rgb) + rgbB[c] + rgbacc[b,c,p]
__global__ void rgbfin_kernel(const float* __restrict__ rgbacc, const void* __restrict__ rgbB,
                              const void* __restrict__ rgb, void* __restrict__ outb,
                              const unsigned* __restrict__ w0raw) {
  __shared__ int shflag;
  const int tid = threadIdx.x;
  const int bf = detect_bf(w0raw, tid, &shflag);
  const int g = blockIdx.x * 256 + tid;  // 0..32767
  const int b = g >> 12, p = g & 4095;
  const int oy = p >> 6, ox = p & 63;
  const int m = oy >> 1; int iy0, iy1; float wy0, wy1;
  if ((oy & 1) == 0) { iy0 = (m > 0) ? m - 1 : 0; iy1 = m; wy0 = 0.25f; wy1 = 0.75f; }
  else               { iy0 = m; iy1 = (m < 31) ? m + 1 : 31; wy0 = 0.75f; wy1 = 0.25f; }
  const int mx = ox >> 1; int ix0, ix1; float wx0, wx1;
  if ((ox & 1) == 0) { ix0 = (mx > 0) ? mx - 1 : 0; ix1 = mx; wx0 = 0.25f; wx1 = 0.75f; }
  else               { ix0 = mx; ix1 = (mx < 31) ? mx + 1 : 31; wx0 = 0.75f; wx1 = 0.25f; }
#pragma unroll
  for (int c = 0; c < 3; ++c) {
    const size_t rb = (size_t)(b * 3 + c) * 1024;
    const float up = wy0 * (wx0 * rin(rgb, rb + iy0 * 32 + ix0, bf) + wx1 * rin(rgb, rb + iy0 * 32 + ix1, bf))
                   + wy1 * (wx0 * rin(rgb, rb + iy1 * 32 + ix0, bf) + wx1 * rin(rgb, rb + iy1 * 32 + ix1, bf));
    const float v = up + rin(rgbB, c, bf) + rgbacc[(size_t)(b * 3 + c) * 4096 + p];
    const size_t oi = ((size_t)(b * 3 + c) << 12) + p;
    if (bf) ((u16*)outb)[oi] = f2b(v); else ((float*)outb)[oi] = v;
  }
}

// ---------------- workspace layout (bytes) ----------------
// s0:1024  s1:17408  sR:33792  dm0:50176  dm1:66560
// zbuf:82944 (8192 B zeroed; B-stage zbuf reads drift up to +1KB within it)
// rgbacc:87040 (393216)  -> 480256
// Wp0:480256 (4718592)  Wp1:5198848 (4718592)
// actB:9917440 (NB=8: 35684352 -> end 45.6MB; NB=4 fallback -> 27.8MB)

extern "C" void kernel_launch(void* const* d_in, const int* in_sizes, int n_in,
                              void* d_out, int out_size, void* d_ws, size_t ws_size,
                              hipStream_t stream) {
  const void* maps   = d_in[0];
  const void* wlat   = d_in[1];
  const void* rgb    = d_in[2];
  const void* noise0 = d_in[3];
  const void* noise1 = d_in[4];
  const void* w0     = d_in[5];
  const void* b0     = d_in[6];
  const void* sW0    = d_in[7];
  const void* sB0    = d_in[8];
  const void* ns0    = d_in[9];
  const void* w1     = d_in[10];
  const void* b1     = d_in[11];
  const void* sW1    = d_in[12];
  const void* sB1    = d_in[13];
  const void* ns1    = d_in[14];
  const void* rgbW   = d_in[15];
  const void* rgbB   = d_in[16];
  const void* rgbSW  = d_in[17];
  const void* rgbSB  = d_in[18];
  const unsigned* w0raw = (const unsigned*)w0;

  char* ws = (char*)d_ws;
  float* s0     = (float*)(ws + 1024);
  float* s1     = (float*)(ws + 17408);
  float* sR     = (float*)(ws + 33792);
  float* dm0    = (float*)(ws + 50176);
  float* dm1    = (float*)(ws + 66560);
  u16*   zbuf   = (u16*)(ws + 82944);
  float* rgbacc = (float*)(ws + 87040);
  u16*   Wp0    = (u16*)(ws + 480256);
  u16*   Wp1    = (u16*)(ws + 5198848);
  u16*   actB   = (u16*)(ws + 9917440);

  // full-batch conv launches (best occupancy) if actB for 8 batches fits in ws
  const bool full = ws_size >= (size_t)(9917440 + 35684352);
  const int NB = full ? 8 : 4;

  styleall_kernel<<<dim3(8, 8, 3), 256, 0, stream>>>(wlat, sW0, sB0, sW1, sB1, rgbSW, rgbSB,
                                                     s0, s1, sR, w0raw);
  demod_kernel<<<dim3(512, 2), 256, 0, stream>>>(w0, w1, s0, s1, dm0, dm1, Wp0, Wp1, w0raw);
  prep_kernel<<<NB * 65 + 97, 256, 0, stream>>>(actB, (u32x4*)zbuf, NB);

  for (int pass = 0; pass < 8 / NB; ++pass) {
    const int b_base = pass * NB;
    upsample_kernel<<<dim3(64, 16, NB), 256, 0, stream>>>(maps, s0, d_out, b_base, w0raw);
    conv_kernel<0><<<dim3(16, 2, NB), 512, 0, stream>>>(d_out, actB, Wp0, dm0,
        b0, ns0, noise0, s1, zbuf, nullptr, nullptr, b_base, w0raw);
    conv_kernel<1><<<dim3(16, 2, NB), 512, 0, stream>>>(d_out, actB, Wp1, dm1,
        b1, ns1, noise1, sR, zbuf, rgbW, rgbacc, b_base, w0raw);
  }
  rgbfin_kernel<<<128, 256, 0, stream>>>(rgbacc, rgbB, rgb, d_out, w0raw);
}

// Round 3
// 432.184 us; speedup vs baseline: 1.1619x; 1.0435x over previous
//
#include <hip/hip_runtime.h>

typedef unsigned short u16;
typedef short bf16x8 __attribute__((ext_vector_type(8)));
typedef float f32x4 __attribute__((ext_vector_type(4)));
typedef u16 u16x4 __attribute__((ext_vector_type(4)));
typedef u16 u16x8 __attribute__((ext_vector_type(8)));
typedef unsigned u32x4 __attribute__((ext_vector_type(4)));

__device__ __forceinline__ float b2f(u16 v) {
  union { unsigned u; float f; } x; x.u = ((unsigned)v) << 16; return x.f;
}
__device__ __forceinline__ u16 f2b(float f) {
  unsigned u = __float_as_uint(f);
  unsigned r = (u + 0x7FFFu + ((u >> 16) & 1u)) >> 16;
  return (u16)r;
}
// dtype-agnostic input read: bf==1 -> bf16, bf==0 -> f32
__device__ __forceinline__ float rin(const void* p, size_t i, int bf) {
  return bf ? b2f(((const u16*)p)[i]) : ((const float*)p)[i];
}
__device__ __forceinline__ void async16(const void* g, void* l) {
  __builtin_amdgcn_global_load_lds((const __attribute__((address_space(1))) unsigned*)g,
                                   (__attribute__((address_space(3))) unsigned*)l, 16, 0, 0);
}
// per-block dtype detection: wave 0 inspects w0's first 64 words (L2-resident),
// broadcasts via LDS. bf16 data -> every low-u16 has plausible small-bf16 exponent.
__device__ __forceinline__ int detect_bf(const unsigned* __restrict__ w0raw, int tid, int* shflag) {
  if (tid < 64) {
    const unsigned lo = w0raw[tid] & 0xFFFFu;
    const unsigned e = (lo >> 7) & 0xFFu;
    const unsigned long long bad = __ballot(e < 100u || e > 126u);
    if (tid == 0) *shflag = (bad == 0ull) ? 1 : 0;
  }
  __syncthreads();
  return *shflag;
}

// ---- all three style GEMMs in one launch: s[b,i] = sum_z w[b,z]*sW[i,z] + sB[i]
__global__ void styleall_kernel(const void* __restrict__ w,
                                const void* __restrict__ sW0, const void* __restrict__ sB0,
                                const void* __restrict__ sW1, const void* __restrict__ sB1,
                                const void* __restrict__ sWR, const void* __restrict__ sBR,
                                float* __restrict__ s0, float* __restrict__ s1,
                                float* __restrict__ sR, const unsigned* __restrict__ w0raw) {
  __shared__ int shflag;
  const int tid = threadIdx.x;
  const int bf = detect_bf(w0raw, tid, &shflag);
  const int mat = blockIdx.z, b = blockIdx.y, oc = blockIdx.x;
  const void* sW = (mat == 0) ? sW0 : ((mat == 1) ? sW1 : sWR);
  const void* sB = (mat == 0) ? sB0 : ((mat == 1) ? sB1 : sBR);
  float* out = (mat == 0) ? s0 : ((mat == 1) ? s1 : sR);
  const int i = oc * 64 + (tid >> 2), q = tid & 3;
  float acc = 0.f;
  if (bf) {
    const u16* rp = (const u16*)sW + (size_t)i * 512 + q * 128;
    const u16* wp = (const u16*)w + b * 512 + q * 128;
    for (int z = 0; z < 128; z += 8) {
      u16x8 a = *(const u16x8*)(rp + z), c = *(const u16x8*)(wp + z);
#pragma unroll
      for (int j = 0; j < 8; ++j) acc += b2f(a[j]) * b2f(c[j]);
    }
  } else {
    const float* rp = (const float*)sW + (size_t)i * 512 + q * 128;
    const float* wp = (const float*)w + b * 512 + q * 128;
    for (int z = 0; z < 128; z += 4) {
      f32x4 a = *(const f32x4*)(rp + z), c = *(const f32x4*)(wp + z);
#pragma unroll
      for (int j = 0; j < 4; ++j) acc += a[j] * c[j];
    }
  }
  acc += __shfl_xor(acc, 1, 64);
  acc += __shfl_xor(acc, 2, 64);
  if (q == 0) out[b * 512 + i] = acc + rin(sB, i, bf);
}

// ---- demod (both layers in one launch, coalesced): block (o, layer).
__global__ void demod_kernel(const void* __restrict__ W0, const void* __restrict__ W1,
                             const float* __restrict__ s0, const float* __restrict__ s1,
                             float* __restrict__ dm0, float* __restrict__ dm1,
                             u16* __restrict__ Wp0, u16* __restrict__ Wp1,
                             const unsigned* __restrict__ w0raw) {
  __shared__ int shflag;
  __shared__ float wl[4608];
  __shared__ float wsq[512];
  const int tid = threadIdx.x, lane = tid & 63, wv = tid >> 6;
  const int bf = detect_bf(w0raw, tid, &shflag);
  const int o = blockIdx.x, layer = blockIdx.y;
  const void* W = layer ? W1 : W0;
  const float* s = layer ? s1 : s0;
  float* d = layer ? dm1 : dm0;
  u16* Wp = layer ? Wp1 : Wp0;

  if (bf) {
    const u16* src = (const u16*)W + (size_t)o * 4608;
    for (int e = tid; e < 576; e += 256) {
      u16x8 v = *(const u16x8*)(src + e * 8);
#pragma unroll
      for (int j = 0; j < 8; ++j) wl[e * 8 + j] = b2f(v[j]);
    }
  } else {
    const float* src = (const float*)W + (size_t)o * 4608;
    for (int e = tid; e < 1152; e += 256) {
      f32x4 v = *(const f32x4*)(src + e * 4);
#pragma unroll
      for (int j = 0; j < 4; ++j) wl[e * 4 + j] = v[j];
    }
  }
  __syncthreads();
  for (int i = tid; i < 512; i += 256) {
    float ss = 0.f;
#pragma unroll
    for (int t = 0; t < 9; ++t) {
      const float f = wl[i * 9 + t];
      ss += f * f;
      Wp[t * 262144 + o * 512 + i] = f2b(f);
    }
    wsq[i] = ss;
  }
  __syncthreads();
#pragma unroll
  for (int bb = 0; bb < 2; ++bb) {
    const int b = wv * 2 + bb;
    float part = 0.f;
    for (int i = lane; i < 512; i += 64) { const float sv = s[b * 512 + i]; part += wsq[i] * sv * sv; }
#pragma unroll
    for (int st = 1; st < 64; st <<= 1) part += __shfl_xor(part, st, 64);
    if (lane == 0) d[b * 512 + o] = rsqrtf(part + 1e-8f);
  }
}

// ---- prep: zero actB's halo ring only (interior is overwritten by conv0) + zbuf/rgbacc
__global__ void prep_kernel(u16* __restrict__ actB, u32x4* __restrict__ zr, int NB) {
  const int id = blockIdx.x, tid = threadIdx.x;
  if (id < NB * 65) {
    const int bl = id / 65, sub = id - bl * 65;
    const int c = sub * 256 + tid;      // 0..16639 : 260 ring px x 64 chunks
    const int px = c >> 6, seg = c & 63;
    int oy, ox;
    if (px < 66)       { oy = 0;  ox = px; }
    else if (px < 132) { oy = 65; ox = px - 66; }
    else { const int e = px - 132; oy = 1 + (e >> 1); ox = (e & 1) * 65; }
    u32x4 z = {0, 0, 0, 0};
    *(u32x4*)&actB[((size_t)(bl * 4356) + oy * 66 + ox) * 512 + seg * 8] = z;
  } else {
    const int c = (id - NB * 65) * 256 + tid;
    if (c < 24832) { u32x4 z = {0, 0, 0, 0}; zr[c] = z; }
  }
}

// ---- bilinear 2x upsample * s0 -> bf16 NHWC scratch [bl][4096][512] inside d_out x-region
// block->image mapping is XCD-aligned (bl = id&7) so conv0's B reads hit the local L2.
__global__ void upsample_kernel(const void* __restrict__ maps, const float* __restrict__ s,
                                void* __restrict__ outb, int b_base,
                                const unsigned* __restrict__ w0raw) {
  __shared__ int shflag;
  __shared__ float it[32][2][33];
  const int tid = threadIdx.x;
  const int bf = detect_bf(w0raw, tid, &shflag);
  const size_t esz = bf ? 2 : 4;
  u16* xg = (u16*)((char*)outb + (98304 + (size_t)(b_base >> 2) * 8388608) * esz);
  int oy, i0, bl;
  if (gridDim.z == 8) {
    const int id = blockIdx.x + (blockIdx.y << 6) + (blockIdx.z << 10);
    bl = id & 7; const int r = id >> 3; oy = r & 63; i0 = (r >> 6) << 5;
  } else {
    oy = blockIdx.x; i0 = blockIdx.y << 5; bl = blockIdx.z;
  }
  const int bg = b_base + bl;
  const int m = oy >> 1;
  int iy0, iy1; float wy0, wy1;
  if ((oy & 1) == 0) { iy0 = (m > 0) ? m - 1 : 0; iy1 = m; wy0 = 0.25f; wy1 = 0.75f; }
  else               { iy0 = m; iy1 = (m < 31) ? m + 1 : 31; wy0 = 0.75f; wy1 = 0.25f; }
#pragma unroll
  for (int k = 0; k < 8; ++k) {
    const int e = tid + k * 256;  // 32c x 2rows x 32x = 2048
    const int c = e >> 6, wsel = (e >> 5) & 1, x = e & 31;
    const int iy = wsel ? iy1 : iy0;
    it[c][wsel][x] = rin(maps, ((size_t)(bg * 512 + i0 + c) * 32 + iy) * 32 + x, bf);
  }
  __syncthreads();
#pragma unroll
  for (int k = 0; k < 8; ++k) {
    const int e = tid + k * 256;  // 64 xx * 32 c = 2048
    const int xx = e >> 5, c = e & 31;
    const int mx = xx >> 1;
    int ix0, ix1; float wx0, wx1;
    if ((xx & 1) == 0) { ix0 = (mx > 0) ? mx - 1 : 0; ix1 = mx; wx0 = 0.25f; wx1 = 0.75f; }
    else               { ix0 = mx; ix1 = (mx < 31) ? mx + 1 : 31; wx0 = 0.75f; wx1 = 0.25f; }
    const float r0 = wx0 * it[c][0][ix0] + wx1 * it[c][0][ix1];
    const float r1 = wx0 * it[c][1][ix0] + wx1 * it[c][1][ix1];
    const float v = (wy0 * r0 + wy1 * r1) * s[bg * 512 + i0 + c];
    xg[((size_t)(bl * 4096) + oy * 64 + xx) * 512 + i0 + c] = f2b(v);
  }
}

// ---- conv (both layers): 256x256 implicit-GEMM tile, BK=64, 8 waves (2Mx4N).
// 2-phase K-step, round-1-style phase shape (reads -> stages -> setprio MFMA with
// compiler-scheduled lgkmcnt -> counted vmcnt -> barrier). 2 barriers + 2 vmcnt
// waits per step (vs 3 in r1, 7 in r2-regression). FIFO ledger per wave
// (stage order: phA issues Ae0,Ae1,Be0,Be1,Bo0,Bo1 of s+1; phB issues Al0,Al1):
//   end-phA vmcnt(6): retires Al(s)        (issued phB of s-1 -> full step of cover)
//   end-phB vmcnt(2): retires Ae/Be/Bo(s+1) (leaves Al(s+1) in flight; never 0)
// LDS read bases loop-carried (XOR 32768/step); stage sources advance +64/step
// with tap-boundary recompute every 8 steps.
template <int L>
__global__ __launch_bounds__(512, 2) void conv_kernel(
    void* __restrict__ outb, u16* __restrict__ actBp,
    const u16* __restrict__ Wp, const float* __restrict__ dmod,
    const void* __restrict__ bias, const void* __restrict__ nsc,
    const void* __restrict__ noise, const float* __restrict__ saux,
    const u16* __restrict__ zbuf, const void* __restrict__ rgbW,
    float* __restrict__ rgbacc, int b_base,
    const unsigned* __restrict__ w0raw) {
  __shared__ __attribute__((aligned(16))) u16 lds[65536];  // [2 dbuf][A 16K u16 | B 16K u16]
  __shared__ float rgbWl[L == 1 ? 1536 : 4];
  __shared__ int shflag;
  const int tid = threadIdx.x, lane = tid & 63, w = tid >> 6;
  const int bf = detect_bf(w0raw, tid, &shflag);
  const size_t esz = bf ? 2 : 4;

  // bijective XCD swizzle: 32 tiles of one image land on one XCD (nwg % 8 == 0)
  const int lin = blockIdx.x + (blockIdx.y << 4) + (blockIdx.z << 5);
  const int cpx = (int)(gridDim.z << 2);            // nwg/8 = 4*NB
  const int wg = (lin & 7) * cpx + (lin >> 3);
  const int bl = wg >> 5, rem = wg & 31;
  const int o0 = (rem >> 4) << 8, n0 = (rem & 15) << 8;
  const int bg = b_base + bl;
  const int wm = w >> 2, wn = w & 3;

  if constexpr (L == 1) {
    for (int e = tid; e < 1536; e += 512) rgbWl[e] = rin(rgbW, e, bf);
  }
  const u16* xg = (const u16*)((const char*)outb +
                  (98304 + (size_t)(b_base >> 2) * 8388608) * esz);

  // fragment-read swizzle: logical chunk c at row r lives at phys chunk c^(r&7)
  const int q = lane >> 4, m15 = lane & 15;
  const int lro = m15 * 64 + ((q ^ (lane & 7)) * 8);   // u16 offset, kk=0; kk=1 => ^32
  // staging source swizzle (linear LDS dest: lane writes row lane>>3, phys chunk lane&7)
  const int srow8 = lane >> 3, schunk = (lane & 7) ^ srow8;
  const size_t aAst = (size_t)(o0 + srow8) * 512 + schunk * 8;

  const int ka0 = (w < 4) ? (2 * w) : (16 + 2 * (w - 4));  // A-early pair base
  const int ka1 = ka0 + 8;                                  // A-late pair base
  const int kbe = (w & 3) * 8 + (w >> 2) * 2;               // B-even pair base
  const int kb0 = kbe, kb1 = kbe + 1, kb2 = kbe + 4, kb3 = kbe + 5;
  int oyv[4], oxv[4];
  size_t pB[4];
  {
    const int kk4[4] = {kb0, kb1, kb2, kb3};
#pragma unroll
    for (int j = 0; j < 4; ++j) {
      const int p = n0 + kk4[j] * 8 + srow8;
      const int oy = p >> 6, ox = p & 63;
      oyv[j] = oy; oxv[j] = ox;
      pB[j] = ((size_t)bl * 4356 + oy * 66 + ox) * 512 + schunk * 8;
    }
  }

  // loop-carried staging state
  const u16* bBase[4];
  int koff, aoffu;
  auto setTap = [&](int tn_) {
    const int ty_ = (tn_ * 11) >> 5, tx_ = tn_ - ty_ * 3;
    koff = 0;
    aoffu = tn_ * 262144;
    if constexpr (L == 0) {
#pragma unroll
      for (int j = 0; j < 4; ++j) {
        const int iy_ = oyv[j] + ty_ - 1, ix_ = oxv[j] + tx_ - 1;
        bBase[j] = (((unsigned)iy_ < 64u) & ((unsigned)ix_ < 64u))
          ? (xg + ((size_t)((bl << 12) + (iy_ << 6) + ix_) * 512 + schunk * 8))
          : (zbuf + schunk * 8);
      }
    } else {
      const int sb_ = (ty_ * 66 + tx_) * 512;
#pragma unroll
      for (int j = 0; j < 4; ++j) bBase[j] = actBp + pB[j] + sb_;
    }
  };

#define STAGE_A(k_) \
  async16(Wp + aAst + (size_t)aoffu + (size_t)(k_) * 4096, &lds[stb + (k_) * 512])
#define STAGE_B(j_, k_) \
  async16(bBase[j_] + koff, &lds[stb + 16384 + (k_) * 512])

  f32x4 acc[8][4] = {};
  {  // prologue: stage K-step 0 into buffer 0 (t=0, ko=0)
    setTap(0);
    const int stb = 0;
    STAGE_A(ka0); STAGE_A(ka0 + 1);
    STAGE_A(ka1); STAGE_A(ka1 + 1);
    STAGE_B(0, kb0); STAGE_B(1, kb1);
    STAGE_B(2, kb2); STAGE_B(3, kb3);
  }
  koff = 64; aoffu = 64;   // state for s1 = 1 (tap 0, kon 64)
  asm volatile("s_waitcnt vmcnt(0)" ::: "memory");
  __builtin_amdgcn_s_barrier();

  // carried LDS read bases (include dbuf bit; XOR 32768 per step)
  int arA  = wm * 8192 + lro;
  int arAx = wm * 8192 + (lro ^ 32);
  int arB  = 16384 + wn * 4096 + lro;
  int arBx = 16384 + wn * 4096 + (lro ^ 32);
  int stb  = 32768;   // stage target buffer (for step s+1)

  bf16x8 afr[4][2], bfA[2][2], bfB[2][2];
#pragma unroll 1
  for (int s = 0; s < 72; ++s) {
    const int s1 = s + 1, ok = (s1 < 72);
    if (ok && (s1 & 7) == 0) setTap(s1 >> 3);

    // ---------- phase A: A-early rows x all 4 B col-groups; prefetch Ae,Be,Bo(s+1)
#pragma unroll
    for (int mi = 0; mi < 4; ++mi) {
      afr[mi][0] = *(const bf16x8*)&lds[arA + mi * 1024];
      afr[mi][1] = *(const bf16x8*)&lds[arAx + mi * 1024];
    }
#pragma unroll
    for (int ni = 0; ni < 2; ++ni) {
      bfA[ni][0] = *(const bf16x8*)&lds[arB + ni * 1024];
      bfA[ni][1] = *(const bf16x8*)&lds[arBx + ni * 1024];
      bfB[ni][0] = *(const bf16x8*)&lds[arB + 2048 + ni * 1024];
      bfB[ni][1] = *(const bf16x8*)&lds[arBx + 2048 + ni * 1024];
    }
    if (ok) {
      STAGE_A(ka0); STAGE_A(ka0 + 1);
      STAGE_B(0, kb0); STAGE_B(1, kb1);
      STAGE_B(2, kb2); STAGE_B(3, kb3);
    }
    __builtin_amdgcn_s_setprio(1);
#pragma unroll
    for (int mi = 0; mi < 4; ++mi)
#pragma unroll
      for (int ni = 0; ni < 2; ++ni)
#pragma unroll
        for (int kk = 0; kk < 2; ++kk)
          acc[mi][ni] = __builtin_amdgcn_mfma_f32_16x16x32_bf16(
              afr[mi][kk], bfA[ni][kk], acc[mi][ni], 0, 0, 0);
#pragma unroll
    for (int mi = 0; mi < 4; ++mi)
#pragma unroll
      for (int ni = 0; ni < 2; ++ni)
#pragma unroll
        for (int kk = 0; kk < 2; ++kk)
          acc[mi][2 + ni] = __builtin_amdgcn_mfma_f32_16x16x32_bf16(
              afr[mi][kk], bfB[ni][kk], acc[mi][2 + ni], 0, 0, 0);
    __builtin_amdgcn_s_setprio(0);
    if (ok) { asm volatile("s_waitcnt vmcnt(6)" ::: "memory"); }
    else    { asm volatile("s_waitcnt vmcnt(0)" ::: "memory"); }
    __builtin_amdgcn_s_barrier();

    // ---------- phase B: A-late rows x all 4 B col-groups; prefetch Al(s+1)
#pragma unroll
    for (int mi = 0; mi < 4; ++mi) {
      afr[mi][0] = *(const bf16x8*)&lds[arA + 4096 + mi * 1024];
      afr[mi][1] = *(const bf16x8*)&lds[arAx + 4096 + mi * 1024];
    }
    if (ok) { STAGE_A(ka1); STAGE_A(ka1 + 1); }
    __builtin_amdgcn_s_setprio(1);
#pragma unroll
    for (int mi = 0; mi < 4; ++mi)
#pragma unroll
      for (int ni = 0; ni < 2; ++ni)
#pragma unroll
        for (int kk = 0; kk < 2; ++kk)
          acc[4 + mi][ni] = __builtin_amdgcn_mfma_f32_16x16x32_bf16(
              afr[mi][kk], bfA[ni][kk], acc[4 + mi][ni], 0, 0, 0);
#pragma unroll
    for (int mi = 0; mi < 4; ++mi)
#pragma unroll
      for (int ni = 0; ni < 2; ++ni)
#pragma unroll
        for (int kk = 0; kk < 2; ++kk)
          acc[4 + mi][2 + ni] = __builtin_amdgcn_mfma_f32_16x16x32_bf16(
              afr[mi][kk], bfB[ni][kk], acc[4 + mi][2 + ni], 0, 0, 0);
    __builtin_amdgcn_s_setprio(0);
    if (ok) { asm volatile("s_waitcnt vmcnt(2)" ::: "memory"); }
    __builtin_amdgcn_s_barrier();

    arA ^= 32768; arAx ^= 32768; arB ^= 32768; arBx ^= 32768; stb ^= 32768;
    koff += 64; aoffu += 64;
  }
#undef STAGE_A
#undef STAGE_B

  if constexpr (L == 0) {
    // epilogue: lrelu(acc*dm + b + ns*noise)*s1 -> actB halo NHWC [bl][66][66][512]
#pragma unroll
    for (int ai = 0; ai < 8; ++ai) {
      const int o = o0 + wm * 128 + ai * 16 + q * 4;
      const f32x4 dv = *(const f32x4*)&dmod[bg * 512 + o];
      const f32x4 sv = *(const f32x4*)&saux[bg * 512 + o];
      float bv[4], nv[4];
#pragma unroll
      for (int r = 0; r < 4; ++r) { bv[r] = rin(bias, o + r, bf); nv[r] = rin(nsc, o + r, bf); }
#pragma unroll
      for (int bj = 0; bj < 4; ++bj) {
        const int p = n0 + wn * 64 + bj * 16 + m15;
        const float np = rin(noise, (size_t)bg * 4096 + p, bf);
        u16x4 pack;
#pragma unroll
        for (int r = 0; r < 4; ++r) {
          float v = acc[ai][bj][r] * dv[r] + bv[r] + nv[r] * np;
          v = (v >= 0.f) ? v : 0.2f * v;
          pack[r] = f2b(v * sv[r]);
        }
        const int oy = p >> 6, ox = p & 63;
        *(u16x4*)&actBp[((size_t)(bl * 4356) + (oy + 1) * 66 + (ox + 1)) * 512 + o] = pack;
      }
    }
  } else {
    // epilogue: x = lrelu(...) -> d_out x-region (dual dtype, NCHW);
    // rgb partials: atomicAdd rgbacc[b][c][p] += sum_o rgbW[c][o]*(x*sR)[o]
    char* xreg = (char*)outb + 98304 * esz;
    float racc[4][3] = {};
#pragma unroll
    for (int ai = 0; ai < 8; ++ai) {
      const int o = o0 + wm * 128 + ai * 16 + q * 4;
      const f32x4 dv = *(const f32x4*)&dmod[bg * 512 + o];
      const f32x4 srv = *(const f32x4*)&saux[bg * 512 + o];
      float bv[4], nv[4], w0l[4], w1l[4], w2l[4];
#pragma unroll
      for (int r = 0; r < 4; ++r) {
        bv[r] = rin(bias, o + r, bf); nv[r] = rin(nsc, o + r, bf);
        w0l[r] = rgbWl[o + r]; w1l[r] = rgbWl[512 + o + r]; w2l[r] = rgbWl[1024 + o + r];
      }
#pragma unroll
      for (int bj = 0; bj < 4; ++bj) {
        const int p = n0 + wn * 64 + bj * 16 + m15;
        const float np = rin(noise, (size_t)bg * 4096 + p, bf);
#pragma unroll
        for (int r = 0; r < 4; ++r) {
          float v = acc[ai][bj][r] * dv[r] + bv[r] + nv[r] * np;
          v = (v >= 0.f) ? v : 0.2f * v;
          const size_t xi = (size_t)(bg * 512 + o + r) * 4096 + p;
          if (bf) ((u16*)xreg)[xi] = f2b(v); else ((float*)xreg)[xi] = v;
          const float xr = v * srv[r];
          racc[bj][0] += w0l[r] * xr;
          racc[bj][1] += w1l[r] * xr;
          racc[bj][2] += w2l[r] * xr;
        }
      }
    }
#pragma unroll
    for (int bj = 0; bj < 4; ++bj) {
      const int p = n0 + wn * 64 + bj * 16 + m15;
#pragma unroll
      for (int c = 0; c < 3; ++c) {
        float t = racc[bj][c];
        t += __shfl_xor(t, 16, 64);
        t += __shfl_xor(t, 32, 64);
        if (lane < 16) atomicAdd(&rgbacc[(size_t)(bg * 3 + c) * 4096 + p], t);
      }
    }
  }
}

// ---- finalize rgb: out[b,c,p] = up2(rgb) + rgbB[c] + rgbacc[b,c,p]
__global__ void rgbfin_kernel(const float* __restrict__ rgbacc, const void* __restrict__ rgbB,
                              const void* __restrict__ rgb, void* __restrict__ outb,
                              const unsigned* __restrict__ w0raw) {
  __shared__ int shflag;
  const int tid = threadIdx.x;
  const int bf = detect_bf(w0raw, tid, &shflag);
  const int g = blockIdx.x * 256 + tid;  // 0..32767
  const int b = g >> 12, p = g & 4095;
  const int oy = p >> 6, ox = p & 63;
  const int m = oy >> 1; int iy0, iy1; float wy0, wy1;
  if ((oy & 1) == 0) { iy0 = (m > 0) ? m - 1 : 0; iy1 = m; wy0 = 0.25f; wy1 = 0.75f; }
  else               { iy0 = m; iy1 = (m < 31) ? m + 1 : 31; wy0 = 0.75f; wy1 = 0.25f; }
  const int mx = ox >> 1; int ix0, ix1; float wx0, wx1;
  if ((ox & 1) == 0) { ix0 = (mx > 0) ? mx - 1 : 0; ix1 = mx; wx0 = 0.25f; wx1 = 0.75f; }
  else               { ix0 = mx; ix1 = (mx < 31) ? mx + 1 : 31; wx0 = 0.75f; wx1 = 0.25f; }
#pragma unroll
  for (int c = 0; c < 3; ++c) {
    const size_t rb = (size_t)(b * 3 + c) * 1024;
    const float up = wy0 * (wx0 * rin(rgb, rb + iy0 * 32 + ix0, bf) + wx1 * rin(rgb, rb + iy0 * 32 + ix1, bf))
                   + wy1 * (wx0 * rin(rgb, rb + iy1 * 32 + ix0, bf) + wx1 * rin(rgb, rb + iy1 * 32 + ix1, bf));
    const float v = up + rin(rgbB, c, bf) + rgbacc[(size_t)(b * 3 + c) * 4096 + p];
    const size_t oi = ((size_t)(b * 3 + c) << 12) + p;
    if (bf) ((u16*)outb)[oi] = f2b(v); else ((float*)outb)[oi] = v;
  }
}

// ---------------- workspace layout (bytes) ----------------
// s0:1024  s1:17408  sR:33792  dm0:50176  dm1:66560
// zbuf:82944 (4096 B zeroed; B-stage zbuf reads drift up to ~2KB within it)
// rgbacc:87040 (393216)  -> 480256
// Wp0:480256 (4718592)  Wp1:5198848 (4718592)
// actB:9917440 (NB=8: 35684352 -> end 45.6MB; NB=4 fallback -> 27.8MB)

extern "C" void kernel_launch(void* const* d_in, const int* in_sizes, int n_in,
                              void* d_out, int out_size, void* d_ws, size_t ws_size,
                              hipStream_t stream) {
  const void* maps   = d_in[0];
  const void* wlat   = d_in[1];
  const void* rgb    = d_in[2];
  const void* noise0 = d_in[3];
  const void* noise1 = d_in[4];
  const void* w0     = d_in[5];
  const void* b0     = d_in[6];
  const void* sW0    = d_in[7];
  const void* sB0    = d_in[8];
  const void* ns0    = d_in[9];
  const void* w1     = d_in[10];
  const void* b1     = d_in[11];
  const void* sW1    = d_in[12];
  const void* sB1    = d_in[13];
  const void* ns1    = d_in[14];
  const void* rgbW   = d_in[15];
  const void* rgbB   = d_in[16];
  const void* rgbSW  = d_in[17];
  const void* rgbSB  = d_in[18];
  const unsigned* w0raw = (const unsigned*)w0;

  char* ws = (char*)d_ws;
  float* s0     = (float*)(ws + 1024);
  float* s1     = (float*)(ws + 17408);
  float* sR     = (float*)(ws + 33792);
  float* dm0    = (float*)(ws + 50176);
  float* dm1    = (float*)(ws + 66560);
  u16*   zbuf   = (u16*)(ws + 82944);
  float* rgbacc = (float*)(ws + 87040);
  u16*   Wp0    = (u16*)(ws + 480256);
  u16*   Wp1    = (u16*)(ws + 5198848);
  u16*   actB   = (u16*)(ws + 9917440);

  // full-batch conv launches (best occupancy) if actB for 8 batches fits in ws
  const bool full = ws_size >= (size_t)(9917440 + 35684352);
  const int NB = full ? 8 : 4;

  styleall_kernel<<<dim3(8, 8, 3), 256, 0, stream>>>(wlat, sW0, sB0, sW1, sB1, rgbSW, rgbSB,
                                                     s0, s1, sR, w0raw);
  demod_kernel<<<dim3(512, 2), 256, 0, stream>>>(w0, w1, s0, s1, dm0, dm1, Wp0, Wp1, w0raw);
  prep_kernel<<<NB * 65 + 97, 256, 0, stream>>>(actB, (u32x4*)zbuf, NB);

  for (int pass = 0; pass < 8 / NB; ++pass) {
    const int b_base = pass * NB;
    upsample_kernel<<<dim3(64, 16, NB), 256, 0, stream>>>(maps, s0, d_out, b_base, w0raw);
    conv_kernel<0><<<dim3(16, 2, NB), 512, 0, stream>>>(d_out, actB, Wp0, dm0,
        b0, ns0, noise0, s1, zbuf, nullptr, nullptr, b_base, w0raw);
    conv_kernel<1><<<dim3(16, 2, NB), 512, 0, stream>>>(d_out, actB, Wp1, dm1,
        b1, ns1, noise1, sR, zbuf, rgbW, rgbacc, b_base, w0raw);
  }
  rgbfin_kernel<<<128, 256, 0, stream>>>(rgbacc, rgbB, rgb, d_out, w0raw);
}